// Round 1
// baseline (450.813 us; speedup 1.0000x reference)
//
#include <hip/hip_runtime.h>
#include <hip/hip_bf16.h>

typedef __attribute__((ext_vector_type(8))) short bf16x8;
typedef __attribute__((ext_vector_type(4))) float f32x4;

#define NB   256
#define TT   512
#define DDEC 512
#define DENC 1024
#define DATT 128
#define NF   32
#define KW   31
#define PW   15

struct SMem {
  __hip_bfloat16 sA[512][72];     // enc tile: 512 x 64 (+8 pad) bf16 = 72KB
  __hip_bfloat16 sBt[128][72];    // Wk chunk transposed [a][kk] = 18KB
  union {
    __hip_bfloat16 locA[512][40]; // conv features [t][f] (+pad) = 40KB
    float part[8][1024];          // phase-2 per-wave partials = 32KB
  } u;
  __hip_bfloat16 locBt[128][40];  // Wloc transposed [a][f] = 10KB
  float attw[TT];
  float qrow[DDEC];
  float cw[NF][32];
  float cb[NF];
  float qv[DATT];
  float wsc[DATT];
  float energy[TT];
  float red[8];
  float scal[2];
};

__device__ __forceinline__ float fast_tanh(float x) {
  float e = __expf(2.f * x);
  return 1.f - 2.f / (e + 1.f);
}

__global__ __launch_bounds__(512, 2) void pass1_kernel(
    const float* __restrict__ query,
    const float* __restrict__ enc,
    const float* __restrict__ attw,
    const float* __restrict__ Wq,
    const float* __restrict__ Wk,
    const float* __restrict__ Wloc,
    const float* __restrict__ convw,
    const float* __restrict__ convb,
    const float* __restrict__ wscore,
    float* __restrict__ out_w,
    float* __restrict__ ctx_enc) {
  __shared__ SMem sm;
  const int b    = blockIdx.x;
  const int tid  = threadIdx.x;
  const int lane = tid & 63;
  const int wv   = tid >> 6;
  const int lrow = lane & 15;
  const int lgrp = lane >> 4;

  // ---------------- phase 0: small loads ----------------
  sm.attw[tid] = attw[(size_t)b * TT + tid];
  sm.qrow[tid] = query[(size_t)b * DDEC + tid];
  for (int i = tid; i < NF * KW; i += 512) sm.cw[i / KW][i % KW] = convw[i];
  if (tid < NF)   sm.cb[tid]  = convb[tid];
  if (tid < DATT) sm.wsc[tid] = wscore[tid];
  for (int i = tid; i < NF * DATT; i += 512) {
    int f = i >> 7, a = i & 127;
    sm.locBt[a][f] = __float2bfloat16(Wloc[i]);
  }
  __syncthreads();

  // q projection (threads 0..127)
  if (tid < DATT) {
    float acc = 0.f;
#pragma unroll 8
    for (int d = 0; d < DDEC; ++d)
      acc = fmaf(sm.qrow[d], Wq[(size_t)d * DATT + tid], acc);
    sm.qv[tid] = acc;
  }
  // conv1d location features: thread t computes all 32 filters
  {
    const int t = tid;
#pragma unroll
    for (int f = 0; f < NF; ++f) {
      float acc = sm.cb[f];
      for (int k = 0; k < KW; ++k) {
        int ts = t - PW + k;
        float x = (ts >= 0 && ts < TT) ? sm.attw[ts] : 0.f;
        acc = fmaf(sm.cw[f][k], x, acc);
      }
      sm.u.locA[t][f] = __float2bfloat16(acc);
    }
  }
  __syncthreads();

  // ---------------- phase 1: energies via MFMA ----------------
  f32x4 acc[4][8];
#pragma unroll
  for (int m = 0; m < 4; ++m)
#pragma unroll
    for (int n = 0; n < 8; ++n) acc[m][n] = (f32x4){0.f, 0.f, 0.f, 0.f};

  const int wrow = wv * 64;

  for (int c = 0; c < 16; ++c) {
    const int k0 = c * 64;
    // stage A: enc[b, 0:512, k0:k0+64] f32 -> bf16 LDS
#pragma unroll
    for (int i = 0; i < 16; ++i) {
      int slot = tid + i * 512;          // 0..8191 over (t, g)
      int t = slot >> 4, g = slot & 15;
      float4 v = *reinterpret_cast<const float4*>(
          enc + (((size_t)b * TT + t) * DENC + k0 + g * 4));
      union { ushort4 u4; __hip_bfloat16 h[4]; } cv;
      cv.h[0] = __float2bfloat16(v.x);
      cv.h[1] = __float2bfloat16(v.y);
      cv.h[2] = __float2bfloat16(v.z);
      cv.h[3] = __float2bfloat16(v.w);
      *reinterpret_cast<ushort4*>(&sm.sA[t][g * 4]) = cv.u4;
    }
    // stage B: Wk[k0:k0+64, 0:128] transposed -> sBt[a][kk]
#pragma unroll
    for (int i = 0; i < 16; ++i) {
      int idx = tid + i * 512;
      int kk = idx >> 7, a = idx & 127;
      sm.sBt[a][kk] = __float2bfloat16(Wk[(size_t)(k0 + kk) * DATT + a]);
    }
    __syncthreads();
#pragma unroll
    for (int s = 0; s < 2; ++s) {
      bf16x8 af[4], bfr[8];
#pragma unroll
      for (int m = 0; m < 4; ++m)
        af[m] = *reinterpret_cast<const bf16x8*>(
            &sm.sA[wrow + m * 16 + lrow][s * 32 + lgrp * 8]);
#pragma unroll
      for (int n = 0; n < 8; ++n)
        bfr[n] = *reinterpret_cast<const bf16x8*>(
            &sm.sBt[n * 16 + lrow][s * 32 + lgrp * 8]);
#pragma unroll
      for (int m = 0; m < 4; ++m)
#pragma unroll
        for (int n = 0; n < 8; ++n)
          acc[m][n] = __builtin_amdgcn_mfma_f32_16x16x32_bf16(
              af[m], bfr[n], acc[m][n], 0, 0, 0);
    }
    __syncthreads();
  }
  // location-feature K=32 step (adds loc @ Wloc)
  {
    bf16x8 af[4], bfr[8];
#pragma unroll
    for (int m = 0; m < 4; ++m)
      af[m] = *reinterpret_cast<const bf16x8*>(
          &sm.u.locA[wrow + m * 16 + lrow][lgrp * 8]);
#pragma unroll
    for (int n = 0; n < 8; ++n)
      bfr[n] = *reinterpret_cast<const bf16x8*>(
          &sm.locBt[n * 16 + lrow][lgrp * 8]);
#pragma unroll
    for (int m = 0; m < 4; ++m)
#pragma unroll
      for (int n = 0; n < 8; ++n)
        acc[m][n] = __builtin_amdgcn_mfma_f32_16x16x32_bf16(
            af[m], bfr[n], acc[m][n], 0, 0, 0);
  }

  // epilogue: energy[t] = sum_a tanh(acc + q[a]) * wscore[a]
#pragma unroll
  for (int m = 0; m < 4; ++m) {
#pragma unroll
    for (int r = 0; r < 4; ++r) {
      float e = 0.f;
#pragma unroll
      for (int n = 0; n < 8; ++n) {
        int col = n * 16 + lrow;
        float v = acc[m][n][r] + sm.qv[col];
        e = fmaf(fast_tanh(v), sm.wsc[col], e);
      }
      e += __shfl_xor(e, 1);
      e += __shfl_xor(e, 2);
      e += __shfl_xor(e, 4);
      e += __shfl_xor(e, 8);
      if (lrow == 0) sm.energy[wrow + m * 16 + lgrp * 4 + r] = e;
    }
  }
  __syncthreads();

  // ---------------- softmax over T (=blockDim) ----------------
  const float e0 = sm.energy[tid];
  float m1 = e0;
#pragma unroll
  for (int off = 1; off < 64; off <<= 1) m1 = fmaxf(m1, __shfl_xor(m1, off));
  if (lane == 0) sm.red[wv] = m1;
  __syncthreads();
  if (tid == 0) {
    float mm = sm.red[0];
#pragma unroll
    for (int i = 1; i < 8; ++i) mm = fmaxf(mm, sm.red[i]);
    sm.scal[0] = mm;
  }
  __syncthreads();
  const float ex = __expf(e0 - sm.scal[0]);
  float s1 = ex;
#pragma unroll
  for (int off = 1; off < 64; off <<= 1) s1 += __shfl_xor(s1, off);
  if (lane == 0) sm.red[wv] = s1;
  __syncthreads();
  if (tid == 0) {
    float ss = 0.f;
#pragma unroll
    for (int i = 0; i < 8; ++i) ss += sm.red[i];
    sm.scal[1] = 1.f / ss;
  }
  __syncthreads();
  const float wnorm = ex * sm.scal[1];
  sm.energy[tid] = wnorm;                    // reuse as weights
  out_w[(size_t)b * TT + tid] = wnorm;
  __syncthreads();

  // ---------------- phase 2: ctx_enc[b,d] = sum_t w[t]*enc[b,t,d] ----------------
  float4 a0 = {0, 0, 0, 0}, a1 = {0, 0, 0, 0}, a2 = {0, 0, 0, 0}, a3 = {0, 0, 0, 0};
  const int t0 = wv * 64;
  for (int tt = 0; tt < 64; ++tt) {
    const int t = t0 + tt;
    const float wt = sm.energy[t];
    const float4* row =
        reinterpret_cast<const float4*>(enc + ((size_t)b * TT + t) * DENC);
    float4 v0 = row[lane];
    float4 v1 = row[64 + lane];
    float4 v2 = row[128 + lane];
    float4 v3 = row[192 + lane];
    a0.x = fmaf(wt, v0.x, a0.x); a0.y = fmaf(wt, v0.y, a0.y);
    a0.z = fmaf(wt, v0.z, a0.z); a0.w = fmaf(wt, v0.w, a0.w);
    a1.x = fmaf(wt, v1.x, a1.x); a1.y = fmaf(wt, v1.y, a1.y);
    a1.z = fmaf(wt, v1.z, a1.z); a1.w = fmaf(wt, v1.w, a1.w);
    a2.x = fmaf(wt, v2.x, a2.x); a2.y = fmaf(wt, v2.y, a2.y);
    a2.z = fmaf(wt, v2.z, a2.z); a2.w = fmaf(wt, v2.w, a2.w);
    a3.x = fmaf(wt, v3.x, a3.x); a3.y = fmaf(wt, v3.y, a3.y);
    a3.z = fmaf(wt, v3.z, a3.z); a3.w = fmaf(wt, v3.w, a3.w);
  }
  *reinterpret_cast<float4*>(&sm.u.part[wv][lane * 4])       = a0;
  *reinterpret_cast<float4*>(&sm.u.part[wv][256 + lane * 4]) = a1;
  *reinterpret_cast<float4*>(&sm.u.part[wv][512 + lane * 4]) = a2;
  *reinterpret_cast<float4*>(&sm.u.part[wv][768 + lane * 4]) = a3;
  __syncthreads();
  for (int d = tid; d < DENC; d += 512) {
    float s = 0.f;
#pragma unroll
    for (int w = 0; w < 8; ++w) s += sm.u.part[w][d];
    ctx_enc[(size_t)b * DENC + d] = s;
  }
}

// context = ctx_enc @ Wv   (256x1024 @ 1024x512)
__global__ __launch_bounds__(512) void ctx_proj_kernel(
    const float* __restrict__ ctx_enc,
    const float* __restrict__ Wv,
    float* __restrict__ out) {
  __shared__ float sc[DENC];
  const int b = blockIdx.x, tid = threadIdx.x;
  for (int i = tid; i < DENC; i += 512) sc[i] = ctx_enc[(size_t)b * DENC + i];
  __syncthreads();
  float acc = 0.f;
#pragma unroll 8
  for (int d = 0; d < DENC; ++d)
    acc = fmaf(sc[d], Wv[(size_t)d * DDEC + tid], acc);
  out[(size_t)b * DDEC + tid] = acc;
}

extern "C" void kernel_launch(void* const* d_in, const int* in_sizes, int n_in,
                              void* d_out, int out_size, void* d_ws, size_t ws_size,
                              hipStream_t stream) {
  const float* query  = (const float*)d_in[0];
  const float* enc    = (const float*)d_in[1];
  const float* attw   = (const float*)d_in[2];
  const float* Wq     = (const float*)d_in[3];
  const float* Wk     = (const float*)d_in[4];
  const float* Wv     = (const float*)d_in[5];
  const float* Wloc   = (const float*)d_in[6];
  const float* convw  = (const float*)d_in[7];
  const float* convb  = (const float*)d_in[8];
  const float* wscore = (const float*)d_in[9];

  float* ctx     = (float*)d_out;               // [256][512]
  float* neww    = (float*)d_out + NB * TT;     // [256][512]
  float* ctx_enc = (float*)d_ws;                // [256][1024] scratch

  hipLaunchKernelGGL(pass1_kernel, dim3(NB), dim3(512), 0, stream,
                     query, enc, attw, Wq, Wk, Wloc, convw, convb, wscore,
                     neww, ctx_enc);
  hipLaunchKernelGGL(ctx_proj_kernel, dim3(NB), dim3(512), 0, stream,
                     ctx_enc, Wv, ctx);
}

// Round 2
// 390.937 us; speedup vs baseline: 1.1532x; 1.1532x over previous
//
#include <hip/hip_runtime.h>
#include <hip/hip_bf16.h>

typedef __attribute__((ext_vector_type(8))) short bf16x8;
typedef __attribute__((ext_vector_type(4))) float f32x4;

#define NB   256
#define TT   512
#define DDEC 512
#define DENC 1024
#define DATT 128
#define NF   32
#define KW   31
#define PW   15

struct SMem {
  union {
    struct {
      __hip_bfloat16 locA[512][40];   // conv features [t][f] (+pad)  40KB
      __hip_bfloat16 locBt[128][40];  // Wloc^T [a][f] (+pad)         10KB
    } l;
    float part[16][1024];             // phase-2 per-wave partials    64KB
  } u;
  float qpart[8][128];                // q-proj partials               4KB
  float attw[TT];
  float qrow[DDEC];
  float cw[NF][32];
  float cb[NF];
  float qv[DATT];
  float wsc[DATT];
  float energy[TT];
  float red[16];
  float scal[2];
};

__device__ __forceinline__ float fast_tanh(float x) {
  float e = __expf(2.f * x);
  return 1.f - 2.f / (e + 1.f);
}

// one-off: WkT[a][k] = bf16(Wk[k][a])   (128 x 1024 bf16 = 256KB, L2/L3-hot)
__global__ __launch_bounds__(256) void prep_wkt(const float* __restrict__ Wk,
                                                __hip_bfloat16* __restrict__ WkT) {
  int idx = blockIdx.x * 256 + threadIdx.x;   // 65536: (k/2, a)
  int k2 = idx >> 7, a = idx & 127;
  int k = k2 * 2;
  union { ushort2 u; __hip_bfloat16 h[2]; } cv;
  cv.h[0] = __float2bfloat16(Wk[(size_t)k * DATT + a]);
  cv.h[1] = __float2bfloat16(Wk[(size_t)(k + 1) * DATT + a]);
  *reinterpret_cast<ushort2*>(WkT + (size_t)a * 1024 + k) = cv.u;
}

__global__ __launch_bounds__(1024) void pass1_kernel(
    const float* __restrict__ query,
    const float* __restrict__ enc,
    const float* __restrict__ attw,
    const float* __restrict__ Wq,
    const __hip_bfloat16* __restrict__ WkT,
    const float* __restrict__ Wloc,
    const float* __restrict__ convw,
    const float* __restrict__ convb,
    const float* __restrict__ wscore,
    float* __restrict__ out_w,
    float* __restrict__ ctx_enc) {
  __shared__ SMem sm;
  const int b    = blockIdx.x;
  const int tid  = threadIdx.x;
  const int lane = tid & 63;
  const int wv   = tid >> 6;          // 0..15, wave owns rows [wv*32, wv*32+32)
  const int lrow = lane & 15;
  const int lgrp = lane >> 4;

  // ---------------- phase 0: small loads ----------------
  if (tid < TT) {
    sm.attw[tid] = attw[(size_t)b * TT + tid];
    sm.qrow[tid] = query[(size_t)b * DDEC + tid];
  }
  if (tid < NF * KW) sm.cw[tid / KW][tid % KW] = convw[tid];
  if (tid < NF)   sm.cb[tid]  = convb[tid];
  if (tid < DATT) sm.wsc[tid] = wscore[tid];
  for (int i = tid; i < NF * DATT; i += 1024) {
    int f = i >> 7, a = i & 127;
    sm.u.l.locBt[a][f] = __float2bfloat16(Wloc[i]);
  }
  __syncthreads();

  // q-proj partials: thread (p,a), p=tid>>7 covers d in [p*64, p*64+64)
  {
    const int p = tid >> 7, a = tid & 127;
    float acc = 0.f;
    const float* wq = Wq + (size_t)(p * 64) * DATT + a;
#pragma unroll 8
    for (int d = 0; d < 64; ++d)
      acc = fmaf(sm.qrow[p * 64 + d], wq[(size_t)d * DATT], acc);
    sm.qpart[p][a] = acc;
  }
  // conv1d location features: thread (h,t) computes filters [h*16, h*16+16)
  {
    const int t = tid & 511, h = tid >> 9;
#pragma unroll
    for (int f0 = 0; f0 < 16; ++f0) {
      const int f = h * 16 + f0;
      float acc = sm.cb[f];
      for (int k = 0; k < KW; ++k) {
        int ts = t - PW + k;
        float x = (ts >= 0 && ts < TT) ? sm.attw[ts] : 0.f;
        acc = fmaf(sm.cw[f][k], x, acc);
      }
      sm.u.l.locA[t][f] = __float2bfloat16(acc);
    }
  }
  __syncthreads();
  if (tid < DATT) {
    float s = 0.f;
#pragma unroll
    for (int p = 0; p < 8; ++p) s += sm.qpart[p][tid];
    sm.qv[tid] = s;
  }

  // ---------------- loc MFMA (K=32) initializes acc ----------------
  f32x4 acc[2][8];
  {
    bf16x8 af[2], bfr[8];
#pragma unroll
    for (int m = 0; m < 2; ++m)
      af[m] = *reinterpret_cast<const bf16x8*>(
          &sm.u.l.locA[wv * 32 + m * 16 + lrow][lgrp * 8]);
#pragma unroll
    for (int n = 0; n < 8; ++n)
      bfr[n] = *reinterpret_cast<const bf16x8*>(
          &sm.u.l.locBt[n * 16 + lrow][lgrp * 8]);
#pragma unroll
    for (int m = 0; m < 2; ++m)
#pragma unroll
      for (int n = 0; n < 8; ++n)
        acc[m][n] = __builtin_amdgcn_mfma_f32_16x16x32_bf16(
            af[m], bfr[n], (f32x4){0.f, 0.f, 0.f, 0.f}, 0, 0, 0);
  }
  __syncthreads();   // qv visible; locA/locBt done (part[] aliases later)

  // ---------------- K-loop: direct global->reg fragments, NO barriers ----------------
  const float* pa0 = enc + (((size_t)b * TT) + wv * 32 + lrow) * DENC + lgrp * 8;
  const __hip_bfloat16* pb = WkT + lrow * 1024 + lgrp * 8;

  for (int c = 0; c < 16; ++c) {
    const int k0 = c * 64;
#pragma unroll
    for (int s = 0; s < 2; ++s) {
      const int ko = k0 + s * 32;
      bf16x8 af[2];
#pragma unroll
      for (int m = 0; m < 2; ++m) {
        const float* p = pa0 + (size_t)m * 16 * DENC + ko;
        float4 v0 = *reinterpret_cast<const float4*>(p);
        float4 v1 = *reinterpret_cast<const float4*>(p + 4);
        union { bf16x8 v; __hip_bfloat16 h[8]; } cv;
        cv.h[0] = __float2bfloat16(v0.x); cv.h[1] = __float2bfloat16(v0.y);
        cv.h[2] = __float2bfloat16(v0.z); cv.h[3] = __float2bfloat16(v0.w);
        cv.h[4] = __float2bfloat16(v1.x); cv.h[5] = __float2bfloat16(v1.y);
        cv.h[6] = __float2bfloat16(v1.z); cv.h[7] = __float2bfloat16(v1.w);
        af[m] = cv.v;
      }
      bf16x8 bfr[8];
#pragma unroll
      for (int n = 0; n < 8; ++n)
        bfr[n] = *reinterpret_cast<const bf16x8*>(pb + (size_t)n * 16 * 1024 + ko);
#pragma unroll
      for (int m = 0; m < 2; ++m)
#pragma unroll
        for (int n = 0; n < 8; ++n)
          acc[m][n] = __builtin_amdgcn_mfma_f32_16x16x32_bf16(
              af[m], bfr[n], acc[m][n], 0, 0, 0);
    }
  }

  // ---------------- epilogue: energy[t] = sum_a tanh(acc+q[a])*wscore[a] ----------------
#pragma unroll
  for (int m = 0; m < 2; ++m) {
#pragma unroll
    for (int r = 0; r < 4; ++r) {
      float e = 0.f;
#pragma unroll
      for (int n = 0; n < 8; ++n) {
        int col = n * 16 + lrow;
        float v = acc[m][n][r] + sm.qv[col];
        e = fmaf(fast_tanh(v), sm.wsc[col], e);
      }
      e += __shfl_xor(e, 1);
      e += __shfl_xor(e, 2);
      e += __shfl_xor(e, 4);
      e += __shfl_xor(e, 8);
      if (lrow == 0) sm.energy[wv * 32 + m * 16 + lgrp * 4 + r] = e;
    }
  }
  __syncthreads();

  // ---------------- softmax over T=512 (1024 threads, hi half idles) ----------------
  const float e0 = (tid < TT) ? sm.energy[tid] : -1e30f;
  float m1 = e0;
#pragma unroll
  for (int off = 1; off < 64; off <<= 1) m1 = fmaxf(m1, __shfl_xor(m1, off));
  if (lane == 0) sm.red[wv] = m1;
  __syncthreads();
  if (tid == 0) {
    float mm = sm.red[0];
#pragma unroll
    for (int i = 1; i < 16; ++i) mm = fmaxf(mm, sm.red[i]);
    sm.scal[0] = mm;
  }
  __syncthreads();
  const float ex = (tid < TT) ? __expf(e0 - sm.scal[0]) : 0.f;
  float s1 = ex;
#pragma unroll
  for (int off = 1; off < 64; off <<= 1) s1 += __shfl_xor(s1, off);
  if (lane == 0) sm.red[wv] = s1;
  __syncthreads();
  if (tid == 0) {
    float ss = 0.f;
#pragma unroll
    for (int i = 0; i < 16; ++i) ss += sm.red[i];
    sm.scal[1] = 1.f / ss;
  }
  __syncthreads();
  if (tid < TT) {
    const float wnorm = ex * sm.scal[1];
    sm.energy[tid] = wnorm;
    out_w[(size_t)b * TT + tid] = wnorm;
  }
  __syncthreads();

  // ---------------- phase 2: ctx_enc[b,d] = sum_t w[t]*enc[b,t,d] ----------------
  float4 a0 = {0,0,0,0}, a1 = {0,0,0,0}, a2 = {0,0,0,0}, a3 = {0,0,0,0};
  const int t0 = wv * 32;
  for (int tt = 0; tt < 32; ++tt) {
    const int t = t0 + tt;
    const float wt = sm.energy[t];
    const float4* row =
        reinterpret_cast<const float4*>(enc + ((size_t)b * TT + t) * DENC);
    float4 v0 = row[lane];
    float4 v1 = row[64 + lane];
    float4 v2 = row[128 + lane];
    float4 v3 = row[192 + lane];
    a0.x = fmaf(wt, v0.x, a0.x); a0.y = fmaf(wt, v0.y, a0.y);
    a0.z = fmaf(wt, v0.z, a0.z); a0.w = fmaf(wt, v0.w, a0.w);
    a1.x = fmaf(wt, v1.x, a1.x); a1.y = fmaf(wt, v1.y, a1.y);
    a1.z = fmaf(wt, v1.z, a1.z); a1.w = fmaf(wt, v1.w, a1.w);
    a2.x = fmaf(wt, v2.x, a2.x); a2.y = fmaf(wt, v2.y, a2.y);
    a2.z = fmaf(wt, v2.z, a2.z); a2.w = fmaf(wt, v2.w, a2.w);
    a3.x = fmaf(wt, v3.x, a3.x); a3.y = fmaf(wt, v3.y, a3.y);
    a3.z = fmaf(wt, v3.z, a3.z); a3.w = fmaf(wt, v3.w, a3.w);
  }
  *reinterpret_cast<float4*>(&sm.u.part[wv][lane * 4])       = a0;
  *reinterpret_cast<float4*>(&sm.u.part[wv][256 + lane * 4]) = a1;
  *reinterpret_cast<float4*>(&sm.u.part[wv][512 + lane * 4]) = a2;
  *reinterpret_cast<float4*>(&sm.u.part[wv][768 + lane * 4]) = a3;
  __syncthreads();
  {
    const int d = tid;   // 1024 threads, one column each
    float s = 0.f;
#pragma unroll
    for (int w = 0; w < 16; ++w) s += sm.u.part[w][d];
    ctx_enc[(size_t)b * DENC + d] = s;
  }
}

// context = ctx_enc @ Wv   (256x1024 @ 1024x512)
__global__ __launch_bounds__(512) void ctx_proj_kernel(
    const float* __restrict__ ctx_enc,
    const float* __restrict__ Wv,
    float* __restrict__ out) {
  __shared__ float sc[DENC];
  const int b = blockIdx.x, tid = threadIdx.x;
  for (int i = tid; i < DENC; i += 512) sc[i] = ctx_enc[(size_t)b * DENC + i];
  __syncthreads();
  float acc = 0.f;
#pragma unroll 8
  for (int d = 0; d < DENC; ++d)
    acc = fmaf(sc[d], Wv[(size_t)d * DDEC + tid], acc);
  out[(size_t)b * DDEC + tid] = acc;
}

extern "C" void kernel_launch(void* const* d_in, const int* in_sizes, int n_in,
                              void* d_out, int out_size, void* d_ws, size_t ws_size,
                              hipStream_t stream) {
  const float* query  = (const float*)d_in[0];
  const float* enc    = (const float*)d_in[1];
  const float* attw   = (const float*)d_in[2];
  const float* Wq     = (const float*)d_in[3];
  const float* Wk     = (const float*)d_in[4];
  const float* Wv     = (const float*)d_in[5];
  const float* Wloc   = (const float*)d_in[6];
  const float* convw  = (const float*)d_in[7];
  const float* convb  = (const float*)d_in[8];
  const float* wscore = (const float*)d_in[9];

  float* ctx     = (float*)d_out;               // [256][512]
  float* neww    = (float*)d_out + NB * TT;     // [256][512]
  float* ctx_enc = (float*)d_ws;                // [256][1024] f32 = 1MB
  __hip_bfloat16* WkT =
      (__hip_bfloat16*)((char*)d_ws + (size_t)NB * DENC * sizeof(float)); // 256KB

  hipLaunchKernelGGL(prep_wkt, dim3(256), dim3(256), 0, stream, Wk, WkT);
  hipLaunchKernelGGL(pass1_kernel, dim3(NB), dim3(1024), 0, stream,
                     query, enc, attw, Wq, WkT, Wloc, convw, convb, wscore,
                     neww, ctx_enc);
  hipLaunchKernelGGL(ctx_proj_kernel, dim3(NB), dim3(512), 0, stream,
                     ctx_enc, Wv, ctx);
}

// Round 3
// 353.702 us; speedup vs baseline: 1.2746x; 1.1053x over previous
//
#include <hip/hip_runtime.h>
#include <hip/hip_bf16.h>

typedef __attribute__((ext_vector_type(8))) short bf16x8;
typedef __attribute__((ext_vector_type(4))) float f32x4;

#define NB   256
#define TT   512
#define DDEC 512
#define DENC 1024
#define DATT 128
#define NF   32
#define KW   31
#define PW   15

// global -> LDS direct DMA, 16B per lane. LDS dest must be wave-uniform base;
// dest = base + lane*16 (linear). Global src is per-lane. (CK-style AS casts.)
#define GLDS16(g, l)                                                        \
  __builtin_amdgcn_global_load_lds(                                         \
      (const __attribute__((address_space(1))) void*)(uintptr_t)(g),        \
      (__attribute__((address_space(3))) void*)(uintptr_t)(l), 16, 0, 0)

struct SMem {
  union {
    struct {
      __hip_bfloat16 locA[512][40];   // conv features [t][f] (+pad)  40KB
      __hip_bfloat16 locBt[128][40];  // Wloc^T [a][f] (+pad)         10KB
    } l;
    char astage[16 * 8192];           // 16 waves x 2 bufs x (32r x 32 f32) 128KB
    float part[16][1024];             // phase-2 per-wave partials    64KB
  } u;
  float qpart[8][128];
  float attw[TT];
  float qrow[DDEC];
  float cw[NF][32];
  float cb[NF];
  float qv[DATT];
  float wsc[DATT];
  float energy[TT];
  float red[16];
  float scal[2];
};

__device__ __forceinline__ float fast_tanh(float x) {
  float e = __expf(2.f * x);
  return 1.f - 2.f / (e + 1.f);
}

// one-off: WkT[a][k] = bf16(Wk[k][a])   (128 x 1024 bf16 = 256KB, L2-hot)
__global__ __launch_bounds__(256) void prep_wkt(const float* __restrict__ Wk,
                                                __hip_bfloat16* __restrict__ WkT) {
  int idx = blockIdx.x * 256 + threadIdx.x;   // 65536: (k/2, a)
  int k2 = idx >> 7, a = idx & 127;
  int k = k2 * 2;
  union { ushort2 u; __hip_bfloat16 h[2]; } cv;
  cv.h[0] = __float2bfloat16(Wk[(size_t)k * DATT + a]);
  cv.h[1] = __float2bfloat16(Wk[(size_t)(k + 1) * DATT + a]);
  *reinterpret_cast<ushort2*>(WkT + (size_t)a * 1024 + k) = cv.u;
}

__global__ __launch_bounds__(1024) void pass1_kernel(
    const float* __restrict__ query,
    const float* __restrict__ enc,
    const float* __restrict__ attw,
    const float* __restrict__ Wq,
    const __hip_bfloat16* __restrict__ WkT,
    const float* __restrict__ Wloc,
    const float* __restrict__ convw,
    const float* __restrict__ convb,
    const float* __restrict__ wscore,
    float* __restrict__ out_w,
    float* __restrict__ ctx_enc) {
  __shared__ SMem sm;
  const int b    = blockIdx.x;
  const int tid  = threadIdx.x;
  const int lane = tid & 63;
  const int wv   = tid >> 6;          // 16 waves, wave owns rows [wv*32, +32)
  const int lrow = lane & 15;
  const int lgrp = lane >> 4;

  // ---------------- phase 0: small loads ----------------
  if (tid < TT) {
    sm.attw[tid] = attw[(size_t)b * TT + tid];
    sm.qrow[tid] = query[(size_t)b * DDEC + tid];
  }
  if (tid < NF * KW) sm.cw[tid / KW][tid % KW] = convw[tid];
  if (tid < NF)   sm.cb[tid]  = convb[tid];
  if (tid < DATT) sm.wsc[tid] = wscore[tid];
  for (int i = tid; i < NF * DATT; i += 1024) {
    int f = i >> 7, a = i & 127;
    sm.u.l.locBt[a][f] = __float2bfloat16(Wloc[i]);
  }
  __syncthreads();

  // q-proj partials: thread (p,a)
  {
    const int p = tid >> 7, a = tid & 127;
    float acc = 0.f;
    const float* wq = Wq + (size_t)(p * 64) * DATT + a;
#pragma unroll 8
    for (int d = 0; d < 64; ++d)
      acc = fmaf(sm.qrow[p * 64 + d], wq[(size_t)d * DATT], acc);
    sm.qpart[p][a] = acc;
  }
  // conv1d location features: thread (h,t) computes filters [h*16, +16)
  {
    const int t = tid & 511, h = tid >> 9;
#pragma unroll
    for (int f0 = 0; f0 < 16; ++f0) {
      const int f = h * 16 + f0;
      float acc = sm.cb[f];
      for (int k = 0; k < KW; ++k) {
        int ts = t - PW + k;
        float x = (ts >= 0 && ts < TT) ? sm.attw[ts] : 0.f;
        acc = fmaf(sm.cw[f][k], x, acc);
      }
      sm.u.l.locA[t][f] = __float2bfloat16(acc);
    }
  }
  __syncthreads();
  if (tid < DATT) {
    float s = 0.f;
#pragma unroll
    for (int p = 0; p < 8; ++p) s += sm.qpart[p][tid];
    sm.qv[tid] = s;
  }

  // ---------------- loc MFMA (K=32) initializes acc ----------------
  f32x4 acc[2][8];
  {
    bf16x8 af[2], bfr[8];
#pragma unroll
    for (int m = 0; m < 2; ++m)
      af[m] = *reinterpret_cast<const bf16x8*>(
          &sm.u.l.locA[wv * 32 + m * 16 + lrow][lgrp * 8]);
#pragma unroll
    for (int n = 0; n < 8; ++n)
      bfr[n] = *reinterpret_cast<const bf16x8*>(
          &sm.u.l.locBt[n * 16 + lrow][lgrp * 8]);
#pragma unroll
    for (int m = 0; m < 2; ++m)
#pragma unroll
      for (int n = 0; n < 8; ++n)
        acc[m][n] = __builtin_amdgcn_mfma_f32_16x16x32_bf16(
            af[m], bfr[n], (f32x4){0.f, 0.f, 0.f, 0.f}, 0, 0, 0);
  }
  __syncthreads();   // loc reads done everywhere; union becomes A-stage space

  // ---------------- K-loop: wave-private DMA double-buffer, NO barriers ----
  // LDS layout per wave: 2 bufs x [32 rows][32 f32], row stride 128B.
  // Swizzle: 16B slot s within a row holds global col-chunk (s ^ (row&7)).
  char* abase = sm.u.astage + wv * 8192;
  const int srow  = lane >> 3;          // 0..7 (row&7 for every i)
  const int swcol = ((lane & 7) ^ srow) * 4;  // float offset within chunk
  const float* gs = enc + ((size_t)b * TT + wv * 32 + srow) * DENC + swcol;

  auto STAGE = [&](int p, int c) {
    const float* g0 = gs + c * 32;
    char* d0 = abase + p * 4096;
#pragma unroll
    for (int i = 0; i < 4; ++i)
      GLDS16(g0 + (size_t)i * 8 * DENC, d0 + i * 1024);
  };

  bf16x8 bfr[8];
  auto LOADB = [&](int c) {
    const __hip_bfloat16* pbc = WkT + (size_t)lrow * 1024 + lgrp * 8 + c * 32;
#pragma unroll
    for (int n = 0; n < 8; ++n)
      bfr[n] = *reinterpret_cast<const bf16x8*>(pbc + (size_t)n * 16 * 1024);
  };

  auto COMPUTE = [&](int cur) {
    const char* rb = abase + cur * 4096;
    bf16x8 af[2];
#pragma unroll
    for (int m = 0; m < 2; ++m) {
      const int row = m * 16 + lrow;
      const int x = (row & 7) << 4;
      float4 f0 = *reinterpret_cast<const float4*>(
          rb + row * 128 + ((lgrp * 32) ^ x));
      float4 f1 = *reinterpret_cast<const float4*>(
          rb + row * 128 + ((lgrp * 32 + 16) ^ x));
      union { bf16x8 v; __hip_bfloat16 h[8]; } cv;
      cv.h[0] = __float2bfloat16(f0.x); cv.h[1] = __float2bfloat16(f0.y);
      cv.h[2] = __float2bfloat16(f0.z); cv.h[3] = __float2bfloat16(f0.w);
      cv.h[4] = __float2bfloat16(f1.x); cv.h[5] = __float2bfloat16(f1.y);
      cv.h[6] = __float2bfloat16(f1.z); cv.h[7] = __float2bfloat16(f1.w);
      af[m] = cv.v;
    }
#pragma unroll
    for (int m = 0; m < 2; ++m)
#pragma unroll
      for (int n = 0; n < 8; ++n)
        acc[m][n] = __builtin_amdgcn_mfma_f32_16x16x32_bf16(
            af[m], bfr[n], acc[m][n], 0, 0, 0);
  };

  STAGE(0, 0);
  int cur = 0;
#pragma unroll 1
  for (int c = 0; c < 31; ++c) {
    LOADB(c);
    STAGE(cur ^ 1, c + 1);
    __builtin_amdgcn_sched_barrier(0);
    // outstanding (FIFO): stage(c)=4, B(c)=8, stage(c+1)=4 -> retire stage(c)
    asm volatile("s_waitcnt vmcnt(12)" ::: "memory");
    __builtin_amdgcn_sched_barrier(0);
    COMPUTE(cur);
    cur ^= 1;
  }
  LOADB(31);
  __builtin_amdgcn_sched_barrier(0);
  // outstanding: stage(31)=4, B(31)=8 -> retire stage(31)
  asm volatile("s_waitcnt vmcnt(8)" ::: "memory");
  __builtin_amdgcn_sched_barrier(0);
  COMPUTE(cur);

  // ---------------- epilogue: energy[t] = sum_a tanh(acc+q[a])*wscore[a] ----
#pragma unroll
  for (int m = 0; m < 2; ++m) {
#pragma unroll
    for (int r = 0; r < 4; ++r) {
      float e = 0.f;
#pragma unroll
      for (int n = 0; n < 8; ++n) {
        int col = n * 16 + lrow;
        float v = acc[m][n][r] + sm.qv[col];
        e = fmaf(fast_tanh(v), sm.wsc[col], e);
      }
      e += __shfl_xor(e, 1);
      e += __shfl_xor(e, 2);
      e += __shfl_xor(e, 4);
      e += __shfl_xor(e, 8);
      if (lrow == 0) sm.energy[wv * 32 + m * 16 + lgrp * 4 + r] = e;
    }
  }
  __syncthreads();

  // ---------------- softmax over T=512 ----------------
  const float e0 = (tid < TT) ? sm.energy[tid] : -1e30f;
  float m1 = e0;
#pragma unroll
  for (int off = 1; off < 64; off <<= 1) m1 = fmaxf(m1, __shfl_xor(m1, off));
  if (lane == 0) sm.red[wv] = m1;
  __syncthreads();
  if (tid == 0) {
    float mm = sm.red[0];
#pragma unroll
    for (int i = 1; i < 16; ++i) mm = fmaxf(mm, sm.red[i]);
    sm.scal[0] = mm;
  }
  __syncthreads();
  const float ex = (tid < TT) ? __expf(e0 - sm.scal[0]) : 0.f;
  float s1 = ex;
#pragma unroll
  for (int off = 1; off < 64; off <<= 1) s1 += __shfl_xor(s1, off);
  if (lane == 0) sm.red[wv] = s1;
  __syncthreads();
  if (tid == 0) {
    float ss = 0.f;
#pragma unroll
    for (int i = 0; i < 16; ++i) ss += sm.red[i];
    sm.scal[1] = 1.f / ss;
  }
  __syncthreads();
  if (tid < TT) {
    const float wnorm = ex * sm.scal[1];
    sm.energy[tid] = wnorm;
    out_w[(size_t)b * TT + tid] = wnorm;
  }
  __syncthreads();

  // ---------------- phase 2: ctx_enc[b,d] = sum_t w[t]*enc[b,t,d] ----------
  float4 a0 = {0,0,0,0}, a1 = {0,0,0,0}, a2 = {0,0,0,0}, a3 = {0,0,0,0};
  const int t0 = wv * 32;
  for (int tt = 0; tt < 32; ++tt) {
    const int t = t0 + tt;
    const float wt = sm.energy[t];
    const float4* row =
        reinterpret_cast<const float4*>(enc + ((size_t)b * TT + t) * DENC);
    float4 v0 = row[lane];
    float4 v1 = row[64 + lane];
    float4 v2 = row[128 + lane];
    float4 v3 = row[192 + lane];
    a0.x = fmaf(wt, v0.x, a0.x); a0.y = fmaf(wt, v0.y, a0.y);
    a0.z = fmaf(wt, v0.z, a0.z); a0.w = fmaf(wt, v0.w, a0.w);
    a1.x = fmaf(wt, v1.x, a1.x); a1.y = fmaf(wt, v1.y, a1.y);
    a1.z = fmaf(wt, v1.z, a1.z); a1.w = fmaf(wt, v1.w, a1.w);
    a2.x = fmaf(wt, v2.x, a2.x); a2.y = fmaf(wt, v2.y, a2.y);
    a2.z = fmaf(wt, v2.z, a2.z); a2.w = fmaf(wt, v2.w, a2.w);
    a3.x = fmaf(wt, v3.x, a3.x); a3.y = fmaf(wt, v3.y, a3.y);
    a3.z = fmaf(wt, v3.z, a3.z); a3.w = fmaf(wt, v3.w, a3.w);
  }
  *reinterpret_cast<float4*>(&sm.u.part[wv][lane * 4])       = a0;
  *reinterpret_cast<float4*>(&sm.u.part[wv][256 + lane * 4]) = a1;
  *reinterpret_cast<float4*>(&sm.u.part[wv][512 + lane * 4]) = a2;
  *reinterpret_cast<float4*>(&sm.u.part[wv][768 + lane * 4]) = a3;
  __syncthreads();
  {
    const int d = tid;
    float s = 0.f;
#pragma unroll
    for (int w = 0; w < 16; ++w) s += sm.u.part[w][d];
    ctx_enc[(size_t)b * DENC + d] = s;
  }
}

// context = ctx_enc @ Wv   (256x1024 @ 1024x512)
__global__ __launch_bounds__(512) void ctx_proj_kernel(
    const float* __restrict__ ctx_enc,
    const float* __restrict__ Wv,
    float* __restrict__ out) {
  __shared__ float sc[DENC];
  const int b = blockIdx.x, tid = threadIdx.x;
  for (int i = tid; i < DENC; i += 512) sc[i] = ctx_enc[(size_t)b * DENC + i];
  __syncthreads();
  float acc = 0.f;
#pragma unroll 8
  for (int d = 0; d < DENC; ++d)
    acc = fmaf(sc[d], Wv[(size_t)d * DDEC + tid], acc);
  out[(size_t)b * DDEC + tid] = acc;
}

extern "C" void kernel_launch(void* const* d_in, const int* in_sizes, int n_in,
                              void* d_out, int out_size, void* d_ws, size_t ws_size,
                              hipStream_t stream) {
  const float* query  = (const float*)d_in[0];
  const float* enc    = (const float*)d_in[1];
  const float* attw   = (const float*)d_in[2];
  const float* Wq     = (const float*)d_in[3];
  const float* Wk     = (const float*)d_in[4];
  const float* Wv     = (const float*)d_in[5];
  const float* Wloc   = (const float*)d_in[6];
  const float* convw  = (const float*)d_in[7];
  const float* convb  = (const float*)d_in[8];
  const float* wscore = (const float*)d_in[9];

  float* ctx     = (float*)d_out;               // [256][512]
  float* neww    = (float*)d_out + NB * TT;     // [256][512]
  float* ctx_enc = (float*)d_ws;                // [256][1024] f32 = 1MB
  __hip_bfloat16* WkT =
      (__hip_bfloat16*)((char*)d_ws + (size_t)NB * DENC * sizeof(float)); // 256KB

  hipLaunchKernelGGL(prep_wkt, dim3(256), dim3(256), 0, stream, Wk, WkT);
  hipLaunchKernelGGL(pass1_kernel, dim3(NB), dim3(1024), 0, stream,
                     query, enc, attw, Wq, WkT, Wloc, convw, convb, wscore,
                     neww, ctx_enc);
  hipLaunchKernelGGL(ctx_proj_kernel, dim3(NB), dim3(512), 0, stream,
                     ctx_enc, Wv, ctx);
}